// Round 5
// baseline (198.396 us; speedup 1.0000x reference)
//
#include <hip/hip_runtime.h>

// CustomAttention: x[2,2048,1024] f32, w_qkv[3072,1024], w_proj[1024,1024], b_proj[1024]
// Round 5: GEMMs upgraded to depth-2 prefetch + counted vmcnt (T4): raw s_barrier,
//          s_waitcnt vmcnt(4) instead of full drain -> load latency hidden under
//          the previous tile's compute. Attention unchanged from round 4.
//   k0: convert_f16: x, w_qkv, w_proj f32 -> f16
//   k1: gemm_f16<0>: qkv -> Qd bf16 (scaled 0.125*log2e), Kd bf16, Vt bf16 [bh][d][n]
//   k2: attn_mfma (bf16 MFMA flash, 8 waves) -> AO f16 [b][n][C]
//   k3: gemm_f16<1>: proj + bias -> d_out f32

constexpr int B_ = 2, N_ = 2048, C_ = 1024, H_ = 16, D_ = 64;
constexpr int M_ = B_ * N_;   // 4096
constexpr int O3 = 3 * C_;    // 3072
constexpr int KVB = 64;
constexpr int NTILES = N_ / KVB;   // 32

typedef short bf16x8 __attribute__((ext_vector_type(8)));
typedef _Float16 half8 __attribute__((ext_vector_type(8)));
typedef _Float16 half4v __attribute__((ext_vector_type(4)));
typedef float f32x4  __attribute__((ext_vector_type(4)));

__device__ __forceinline__ unsigned short f2bf(float f) {
    unsigned int u = __float_as_uint(f);
    unsigned int r = (u + 0x7FFFu + ((u >> 16) & 1u)) >> 16;
    return (unsigned short)r;
}

__device__ __forceinline__ void async16(const void* g, void* l) {
    __builtin_amdgcn_global_load_lds(
        (const __attribute__((address_space(1))) unsigned int*)g,
        (__attribute__((address_space(3))) unsigned int*)l, 16, 0, 0);
}

// ---------------- f32 -> f16 convert (x | w_qkv | w_proj) ----------------
constexpr size_t XN  = (size_t)M_ * C_;        // 4,194,304
constexpr size_t WQN = (size_t)O3 * C_;        // 3,145,728
constexpr size_t WPN = (size_t)C_ * C_;        // 1,048,576

__global__ __launch_bounds__(256)
void convert_f16(const float* __restrict__ x, const float* __restrict__ wq,
                 const float* __restrict__ wp, _Float16* __restrict__ dst)
{
    size_t i = ((size_t)blockIdx.x * 256 + threadIdx.x) * 8;
    const float* src;
    size_t off;
    if (i < XN)            { src = x;  off = i; }
    else if (i < XN + WQN) { src = wq; off = i - XN; }
    else                   { src = wp; off = i - XN - WQN; }
    float4 a = *(const float4*)(src + off);
    float4 b = *(const float4*)(src + off + 4);
    half8 h;
    h[0] = (_Float16)a.x; h[1] = (_Float16)a.y; h[2] = (_Float16)a.z; h[3] = (_Float16)a.w;
    h[4] = (_Float16)b.x; h[5] = (_Float16)b.y; h[6] = (_Float16)b.z; h[7] = (_Float16)b.w;
    *(half8*)(dst + i) = h;
}

// ---------------- f16 MFMA GEMM (128x128, BK=32, depth-2 counted-vmcnt) --------
// LDS per tile: [ks(0..3)][row(0..127)][16B]. Frags (16x16x32): A row=lane&15,
// k=8*(lane>>4)+e ; B col=lane&15 same k ; C/D col=lane&15, row=4*(lane>>4)+reg.
// Pipeline: tiles t and t+1 in flight; per iter: vmcnt(4) -> s_barrier -> compute
// -> s_barrier -> stage(t+2 into just-consumed buffer). No vmcnt(0) in main loop.
template<int MODE>
__global__ __launch_bounds__(256)
void gemm_f16(const _Float16* __restrict__ Ag, const _Float16* __restrict__ Bg,
              unsigned short* __restrict__ Qd, unsigned short* __restrict__ Kd,
              unsigned short* __restrict__ Vt,
              const float* __restrict__ bias, float* __restrict__ Out)
{
    __shared__ __align__(16) unsigned char Ab[2][8192];
    __shared__ __align__(16) unsigned char Bb[2][8192];

    const int t    = threadIdx.x;
    const int lane = t & 63;
    const int w    = t >> 6;
    const int g    = lane >> 4;
    const int c    = lane & 15;
    const int wm   = w >> 1, wn = w & 1;
    const int bm   = blockIdx.y * 128;
    const int bn   = blockIdx.x * 128;
    constexpr int K = C_;

    f32x4 acc[4][4];
    f32x4 zero = {0.f, 0.f, 0.f, 0.f};
    #pragma unroll
    for (int mi = 0; mi < 4; ++mi)
        #pragma unroll
        for (int ni = 0; ni < 4; ++ni) acc[mi][ni] = zero;

    auto stage = [&](int buf, int k0) {
        #pragma unroll
        for (int i = 0; i < 2; ++i) {
            int id  = t + 256 * i;       // cell = [ks][row]
            int ks  = id >> 7;
            int row = id & 127;
            int ldsb = (w * 64 + i * 256) * 16;
            async16(Ag + (size_t)(bm + row) * K + k0 + 8 * ks, &Ab[buf][ldsb]);
            async16(Bg + (size_t)(bn + row) * K + k0 + 8 * ks, &Bb[buf][ldsb]);
        }
    };

    // depth-2 prologue: tiles 0 and 1 in flight
    stage(0, 0);
    stage(1, 32);
    int cur = 0;

    for (int k0 = 0; k0 < K; k0 += 32) {
        // wait: current tile's 4 loads landed; next tile's 4 may stay in flight
        if (k0 + 32 < K) asm volatile("s_waitcnt vmcnt(4)" ::: "memory");
        else             asm volatile("s_waitcnt vmcnt(0)" ::: "memory");
        __builtin_amdgcn_s_barrier();
        __builtin_amdgcn_sched_barrier(0);

        const unsigned char* Abase = &Ab[cur][g * 2048];
        const unsigned char* Bbase = &Bb[cur][g * 2048];
        half8 af[4], bf[4];
        #pragma unroll
        for (int mi = 0; mi < 4; ++mi)
            af[mi] = *(const half8*)(Abase + (wm * 64 + mi * 16 + c) * 16);
        #pragma unroll
        for (int ni = 0; ni < 4; ++ni)
            bf[ni] = *(const half8*)(Bbase + (wn * 64 + ni * 16 + c) * 16);
        #pragma unroll
        for (int mi = 0; mi < 4; ++mi)
            #pragma unroll
            for (int ni = 0; ni < 4; ++ni)
                acc[mi][ni] = __builtin_amdgcn_mfma_f32_16x16x32_f16(af[mi], bf[ni], acc[mi][ni], 0, 0, 0);

        __builtin_amdgcn_sched_barrier(0);
        __builtin_amdgcn_s_barrier();      // all waves done reading buf[cur]
        __builtin_amdgcn_sched_barrier(0);
        if (k0 + 64 < K) stage(cur, k0 + 64);   // refill just-consumed buffer
        cur ^= 1;
    }

    if constexpr (MODE == 0) {
        constexpr float QSCALE = 0.125f * 1.4426950408889634f;   // D^-0.5 * log2(e)
        const int which = bn >> 10;
        const int h  = (((bn & 1023) + wn * 64) >> 6);
        const int b  = (bm + wm * 64) >> 11;
        const int n0 = (bm + wm * 64) & 2047;
        const size_t bh = (size_t)b * H_ + h;
        if (which == 0) {
            unsigned short* base = Qd + (bh * N_) * D_;
            #pragma unroll
            for (int mi = 0; mi < 4; ++mi)
                #pragma unroll
                for (int ni = 0; ni < 4; ++ni)
                    #pragma unroll
                    for (int r = 0; r < 4; ++r)
                        base[(size_t)(n0 + mi * 16 + 4 * g + r) * D_ + ni * 16 + c] =
                            f2bf(acc[mi][ni][r] * QSCALE);
        } else if (which == 1) {
            unsigned short* base = Kd + (bh * N_) * D_;
            #pragma unroll
            for (int mi = 0; mi < 4; ++mi)
                #pragma unroll
                for (int ni = 0; ni < 4; ++ni)
                    #pragma unroll
                    for (int r = 0; r < 4; ++r)
                        base[(size_t)(n0 + mi * 16 + 4 * g + r) * D_ + ni * 16 + c] =
                            f2bf(acc[mi][ni][r]);
        } else {
            unsigned short* base = Vt + (bh * D_) * (size_t)N_;
            #pragma unroll
            for (int mi = 0; mi < 4; ++mi)
                #pragma unroll
                for (int ni = 0; ni < 4; ++ni) {
                    ushort4 v;
                    v.x = f2bf(acc[mi][ni][0]);
                    v.y = f2bf(acc[mi][ni][1]);
                    v.z = f2bf(acc[mi][ni][2]);
                    v.w = f2bf(acc[mi][ni][3]);
                    *(ushort4*)&base[(size_t)(ni * 16 + c) * N_ + n0 + mi * 16 + 4 * g] = v;
                }
        }
    } else {
        const int m0 = bm + wm * 64;
        const int o0 = bn + wn * 64;
        #pragma unroll
        for (int ni = 0; ni < 4; ++ni) {
            float bb = bias[o0 + ni * 16 + c];
            #pragma unroll
            for (int mi = 0; mi < 4; ++mi)
                #pragma unroll
                for (int r = 0; r < 4; ++r)
                    Out[(size_t)(m0 + mi * 16 + 4 * g + r) * C_ + o0 + ni * 16 + c] =
                        acc[mi][ni][r] + bb;
        }
    }
}

// ---------------- MFMA flash attention: 8 waves, 128 q rows per block ----------
__global__ __launch_bounds__(512)
void attn_mfma(const unsigned short* __restrict__ Qd, const unsigned short* __restrict__ Kd,
               const unsigned short* __restrict__ Vt, _Float16* __restrict__ AO)
{
    __shared__ __align__(16) unsigned char KsB[2][64 * 128];  // K tile  [key][d] bf16, swz
    __shared__ __align__(16) unsigned char VtB[2][64 * 128];  // V^T tile [d][key] bf16, swz
    __shared__ __align__(16) unsigned char Pb[8][16 * 128];   // per-wave P [q][key] bf16, swz

    const int t    = threadIdx.x;
    const int lane = t & 63;
    const int w    = t >> 6;                 // 0..7
    const int g    = lane >> 4;
    const int c    = lane & 15;
    const int cx   = c & 7;

    // bijective XCD swizzle: 512 blocks, 64 works/XCD -> 4 consecutive bh per XCD
    int flat = blockIdx.x;
    int work = (flat & 7) * 64 + (flat >> 3);
    const int bh = work >> 4;               // 0..31
    const int qt = work & 15;               // 0..15
    const int b  = bh >> 4, h = bh & 15;
    const int q0 = qt * 128;

    const unsigned short* Kp = Kd + (size_t)bh * N_ * D_;
    const unsigned short* Vp = Vt + (size_t)bh * D_ * N_;

    const unsigned short* qp = Qd + ((size_t)bh * N_ + q0 + w * 16 + c) * D_;
    bf16x8 qf0 = *(const bf16x8*)(qp + 8 * g);
    bf16x8 qf1 = *(const bf16x8*)(qp + 32 + 8 * g);

    const int rk = t >> 3, pk = t & 7;       // K: row 0..63, granule
    const unsigned char* kSrc = (const unsigned char*)Kp + rk * 128 + ((pk ^ (rk & 7)) << 4);
    const unsigned char* vSrc = (const unsigned char*)Vp + (size_t)rk * N_ * 2 + ((pk ^ (rk & 7)) << 4);
    unsigned char* kDstA = KsB[0] + t * 16;
    unsigned char* kDstB = KsB[1] + t * 16;
    unsigned char* vDstA = VtB[0] + t * 16;
    unsigned char* vDstB = VtB[1] + t * 16;

    float m_run = -1e30f, l_run = 0.f;
    f32x4 oc[4];
    f32x4 zero = {0.f, 0.f, 0.f, 0.f};
    #pragma unroll
    for (int dc = 0; dc < 4; ++dc) oc[dc] = zero;

    async16(kSrc, kDstA);
    async16(vSrc, vDstA);
    __syncthreads();

    int cur = 0;
    for (int kt = 0; kt < NTILES; ++kt) {
        if (kt + 1 < NTILES) {
            const unsigned char* ks = kSrc + (size_t)(kt + 1) * KVB * 128;
            const unsigned char* vs = vSrc + (size_t)(kt + 1) * 128;
            async16(ks, cur ? kDstA : kDstB);
            async16(vs, cur ? vDstA : vDstB);
        }

        // ---- S^T = K * Q^T  (rows = keys, cols = q = c) ----
        const unsigned char* kbase = KsB[cur];
        f32x4 st[4];
        #pragma unroll
        for (int tt = 0; tt < 4; ++tt) st[tt] = zero;
        __builtin_amdgcn_s_setprio(1);
        #pragma unroll
        for (int s = 0; s < 2; ++s) {
            bf16x8 qf = s ? qf1 : qf0;
            #pragma unroll
            for (int tt = 0; tt < 4; ++tt) {
                bf16x8 a = *(const bf16x8*)(kbase + (tt * 16 + c) * 128 + (((4 * s + g) ^ cx) << 4));
                st[tt] = __builtin_amdgcn_mfma_f32_16x16x32_bf16(a, qf, st[tt], 0, 0, 0);
            }
        }
        __builtin_amdgcn_s_setprio(0);

        // ---- online softmax with defer-max (THR = 8 in log2 domain) ----
        float mx = st[0][0];
        #pragma unroll
        for (int tt = 0; tt < 4; ++tt)
            #pragma unroll
            for (int r = 0; r < 4; ++r) mx = fmaxf(mx, st[tt][r]);
        mx = fmaxf(mx, __shfl_xor(mx, 16));
        mx = fmaxf(mx, __shfl_xor(mx, 32));
        const bool defer = __all(mx <= m_run + 8.f);
        const float nm = defer ? m_run : fmaxf(m_run, mx);
        float ts = 0.f;
        #pragma unroll
        for (int tt = 0; tt < 4; ++tt)
            #pragma unroll
            for (int r = 0; r < 4; ++r) {
                float p = exp2f(st[tt][r] - nm);
                st[tt][r] = p;
                ts += p;
            }
        ts += __shfl_xor(ts, 16);
        ts += __shfl_xor(ts, 32);
        if (defer) {
            l_run += ts;
        } else {
            float corr = exp2f(m_run - nm);
            l_run = l_run * corr + ts;
            m_run = nm;
            #pragma unroll
            for (int dc = 0; dc < 4; ++dc) oc[dc] *= corr;
        }

        // ---- pack P (truncate to bf16) -> wave-private LDS [q=c][key] ----
        unsigned char* pw = Pb[w] + c * 128;
        #pragma unroll
        for (int tt = 0; tt < 4; ++tt) {
            unsigned int lo = __byte_perm(__float_as_uint(st[tt][0]), __float_as_uint(st[tt][1]), 0x7632);
            unsigned int hi = __byte_perm(__float_as_uint(st[tt][2]), __float_as_uint(st[tt][3]), 0x7632);
            int gran = 2 * tt + (g >> 1);
            unsigned int* dst = (unsigned int*)(pw + ((gran ^ cx) << 4) + 8 * (g & 1));
            dst[0] = lo;
            dst[1] = hi;
        }

        // ---- out^T += V^T * P  (rows d, cols q = c) ----
        const unsigned char* vb = VtB[cur];
        const unsigned char* prd = Pb[w] + c * 128;
        bf16x8 pb0 = *(const bf16x8*)(prd + ((g ^ cx) << 4));
        bf16x8 pb1 = *(const bf16x8*)(prd + (((4 + g) ^ cx) << 4));
        __builtin_amdgcn_s_setprio(1);
        #pragma unroll
        for (int dc = 0; dc < 4; ++dc) {
            const unsigned char* vrow = vb + (dc * 16 + c) * 128;
            bf16x8 a0 = *(const bf16x8*)(vrow + ((g ^ cx) << 4));
            bf16x8 a1 = *(const bf16x8*)(vrow + (((4 + g) ^ cx) << 4));
            oc[dc] = __builtin_amdgcn_mfma_f32_16x16x32_bf16(a0, pb0, oc[dc], 0, 0, 0);
            oc[dc] = __builtin_amdgcn_mfma_f32_16x16x32_bf16(a1, pb1, oc[dc], 0, 0, 0);
        }
        __builtin_amdgcn_s_setprio(0);

        __syncthreads();   // drains vmcnt (stage done) + protects buffer swap
        cur ^= 1;
    }

    // ---- epilogue: normalize, write AO f16 [b][q][h*64+d] ----
    float inv = 1.0f / l_run;
    int q = q0 + w * 16 + c;
    _Float16* aop = AO + ((size_t)b * N_ + q) * C_ + h * D_;
    #pragma unroll
    for (int dc = 0; dc < 4; ++dc) {
        half4v o;
        o[0] = (_Float16)(oc[dc][0] * inv);
        o[1] = (_Float16)(oc[dc][1] * inv);
        o[2] = (_Float16)(oc[dc][2] * inv);
        o[3] = (_Float16)(oc[dc][3] * inv);
        *(half4v*)(aop + dc * 16 + 4 * g) = o;
    }
}

extern "C" void kernel_launch(void* const* d_in, const int* in_sizes, int n_in,
                              void* d_out, int out_size, void* d_ws, size_t ws_size,
                              hipStream_t stream) {
    const float* x      = (const float*)d_in[0];
    const float* w_qkv  = (const float*)d_in[1];
    const float* w_proj = (const float*)d_in[2];
    const float* b_proj = (const float*)d_in[3];
    float* out = (float*)d_out;

    const size_t hd = (size_t)B_ * H_ * N_ * D_;   // 4,194,304 elems
    unsigned short* Qd = (unsigned short*)d_ws;
    unsigned short* Kd = Qd + hd;
    unsigned short* Vt = Kd + hd;
    _Float16* AO  = (_Float16*)(Vt + hd);          // [B,N,C] f16
    _Float16* x16 = AO + hd;                       // [4096][1024]
    _Float16* wq16 = x16 + XN;                     // [3072][1024]
    _Float16* wp16 = wq16 + WQN;                   // [1024][1024]

    convert_f16<<<4096, 256, 0, stream>>>(x, w_qkv, w_proj, x16);
    gemm_f16<0><<<dim3(O3 / 128, M_ / 128), 256, 0, stream>>>(
        x16, wq16, Qd, Kd, Vt, nullptr, nullptr);
    attn_mfma<<<dim3(512), 512, 0, stream>>>(Qd, Kd, Vt, AO);
    gemm_f16<1><<<dim3(C_ / 128, M_ / 128), 256, 0, stream>>>(
        AO, wp16, nullptr, nullptr, nullptr, b_proj, out);
}

// Round 6
// 184.551 us; speedup vs baseline: 1.0750x; 1.0750x over previous
//
#include <hip/hip_runtime.h>

// CustomAttention: x[2,2048,1024] f32, w_qkv[3072,1024], w_proj[1024,1024], b_proj[1024]
// Round 6: qkv GEMM -> 256x256/BK=64/8-wave 2-phase (m230-V0 structure, amortizes
//          the per-tile drain over 4x MFMA); proj GEMM reverted to round-4 128x128
//          (round-5 counted-vmcnt experiment regressed: compiler inserts its own
//          vmcnt(0) before aliasing ds_reads). Attention unchanged.
//   k0: convert_f16: x, w_qkv, w_proj f32 -> f16
//   k1: gemm_qkv (256^2): -> Qd bf16 (scaled 0.125*log2e), Kd bf16, Vt bf16 [bh][d][n]
//   k2: attn_mfma (bf16 MFMA flash, 8 waves) -> AO f16 [b][n][C]
//   k3: gemm_proj (128^2, round-4 structure): + bias -> d_out f32

constexpr int B_ = 2, N_ = 2048, C_ = 1024, H_ = 16, D_ = 64;
constexpr int M_ = B_ * N_;   // 4096
constexpr int O3 = 3 * C_;    // 3072
constexpr int KVB = 64;
constexpr int NTILES = N_ / KVB;   // 32

typedef short bf16x8 __attribute__((ext_vector_type(8)));
typedef _Float16 half8 __attribute__((ext_vector_type(8)));
typedef _Float16 half4v __attribute__((ext_vector_type(4)));
typedef float f32x4  __attribute__((ext_vector_type(4)));

__device__ __forceinline__ unsigned short f2bf(float f) {
    unsigned int u = __float_as_uint(f);
    unsigned int r = (u + 0x7FFFu + ((u >> 16) & 1u)) >> 16;
    return (unsigned short)r;
}

__device__ __forceinline__ void async16(const void* g, void* l) {
    __builtin_amdgcn_global_load_lds(
        (const __attribute__((address_space(1))) unsigned int*)g,
        (__attribute__((address_space(3))) unsigned int*)l, 16, 0, 0);
}

// ---------------- f32 -> f16 convert (x | w_qkv | w_proj) ----------------
constexpr size_t XN  = (size_t)M_ * C_;        // 4,194,304
constexpr size_t WQN = (size_t)O3 * C_;        // 3,145,728
constexpr size_t WPN = (size_t)C_ * C_;        // 1,048,576

__global__ __launch_bounds__(256)
void convert_f16(const float* __restrict__ x, const float* __restrict__ wq,
                 const float* __restrict__ wp, _Float16* __restrict__ dst)
{
    size_t i = ((size_t)blockIdx.x * 256 + threadIdx.x) * 8;
    const float* src;
    size_t off;
    if (i < XN)            { src = x;  off = i; }
    else if (i < XN + WQN) { src = wq; off = i - XN; }
    else                   { src = wp; off = i - XN - WQN; }
    float4 a = *(const float4*)(src + off);
    float4 b = *(const float4*)(src + off + 4);
    half8 h;
    h[0] = (_Float16)a.x; h[1] = (_Float16)a.y; h[2] = (_Float16)a.z; h[3] = (_Float16)a.w;
    h[4] = (_Float16)b.x; h[5] = (_Float16)b.y; h[6] = (_Float16)b.z; h[7] = (_Float16)b.w;
    *(half8*)(dst + i) = h;
}

// ---------------- QKV GEMM: 256x256 tile, BK=64, 8 waves, 2-phase ----------------
// LDS per tile per operand: [kgran(0..7)][row(0..255)][16B] = 32KB; dbuf -> 128KB.
// Frags (16x16x32): A row=lane&15, k=8*(lane>>4)+e ; B col=lane&15 same k ;
// C/D col=lane&15, row=4*(lane>>4)+reg.
// Waves: 2M x 4N; per-wave out 128x64 -> acc[8][4], 64 MFMA per K-tile.
__global__ __launch_bounds__(512)
void gemm_qkv(const _Float16* __restrict__ Ag, const _Float16* __restrict__ Bg,
              unsigned short* __restrict__ Qd, unsigned short* __restrict__ Kd,
              unsigned short* __restrict__ Vt)
{
    __shared__ __align__(16) unsigned char Ab[2][32768];
    __shared__ __align__(16) unsigned char Bb[2][32768];

    const int t    = threadIdx.x;
    const int lane = t & 63;
    const int w    = t >> 6;          // 0..7
    const int g    = lane >> 4;
    const int c    = lane & 15;
    const int wm   = w >> 2;          // 0..1  (M half)
    const int wn   = w & 3;           // 0..3  (N quarter)
    const int bm   = blockIdx.y * 256;
    const int bn   = blockIdx.x * 256;
    constexpr int K = C_;

    f32x4 acc[8][4];
    f32x4 zero = {0.f, 0.f, 0.f, 0.f};
    #pragma unroll
    for (int mi = 0; mi < 8; ++mi)
        #pragma unroll
        for (int ni = 0; ni < 4; ++ni) acc[mi][ni] = zero;

    auto stage = [&](int buf, int k0) {
        #pragma unroll
        for (int i = 0; i < 4; ++i) {
            int id  = t + 512 * i;     // cell = kgran*256 + row
            int ks  = id >> 8;         // 0..7
            int row = id & 255;
            async16(Ag + (size_t)(bm + row) * K + k0 + 8 * ks, &Ab[buf][id * 16]);
            async16(Bg + (size_t)(bn + row) * K + k0 + 8 * ks, &Bb[buf][id * 16]);
        }
    };

    stage(0, 0);
    __syncthreads();
    int cur = 0;

    for (int k0 = 0; k0 < K; k0 += 64) {
        if (k0 + 64 < K) stage(cur ^ 1, k0 + 64);   // prefetch next tile

        const unsigned char* Abase = Ab[cur];
        const unsigned char* Bbase = Bb[cur];
        #pragma unroll
        for (int s = 0; s < 2; ++s) {              // two k-slices of 32
            const int ksg = (s * 4 + g) * 256;
            half8 af[8], bfr[4];
            #pragma unroll
            for (int mi = 0; mi < 8; ++mi)
                af[mi] = *(const half8*)(Abase + (ksg + wm * 128 + mi * 16 + c) * 16);
            #pragma unroll
            for (int ni = 0; ni < 4; ++ni)
                bfr[ni] = *(const half8*)(Bbase + (ksg + wn * 64 + ni * 16 + c) * 16);
            #pragma unroll
            for (int mi = 0; mi < 8; ++mi)
                #pragma unroll
                for (int ni = 0; ni < 4; ++ni)
                    acc[mi][ni] = __builtin_amdgcn_mfma_f32_16x16x32_f16(af[mi], bfr[ni], acc[mi][ni], 0, 0, 0);
        }

        __syncthreads();   // drains this iter's prefetch + protects buffer swap
        cur ^= 1;
    }

    // scatter epilogue: o = which*1024 + h*64 + d  (256-col block never straddles which)
    constexpr float QSCALE = 0.125f * 1.4426950408889634f;   // D^-0.5 * log2(e)
    const int which = bn >> 10;
    const int h  = (((bn & 1023) + wn * 64) >> 6);
    const int mrow0 = bm + wm * 128;
    const int b  = mrow0 >> 11;
    const int n0 = mrow0 & 2047;
    const size_t bh = (size_t)b * H_ + h;
    if (which == 0) {
        unsigned short* base = Qd + (bh * N_) * D_;
        #pragma unroll
        for (int mi = 0; mi < 8; ++mi)
            #pragma unroll
            for (int ni = 0; ni < 4; ++ni)
                #pragma unroll
                for (int r = 0; r < 4; ++r)
                    base[(size_t)(n0 + mi * 16 + 4 * g + r) * D_ + ni * 16 + c] =
                        f2bf(acc[mi][ni][r] * QSCALE);
    } else if (which == 1) {
        unsigned short* base = Kd + (bh * N_) * D_;
        #pragma unroll
        for (int mi = 0; mi < 8; ++mi)
            #pragma unroll
            for (int ni = 0; ni < 4; ++ni)
                #pragma unroll
                for (int r = 0; r < 4; ++r)
                    base[(size_t)(n0 + mi * 16 + 4 * g + r) * D_ + ni * 16 + c] =
                        f2bf(acc[mi][ni][r]);
    } else {
        unsigned short* base = Vt + (bh * D_) * (size_t)N_;
        #pragma unroll
        for (int mi = 0; mi < 8; ++mi)
            #pragma unroll
            for (int ni = 0; ni < 4; ++ni) {
                ushort4 v;
                v.x = f2bf(acc[mi][ni][0]);
                v.y = f2bf(acc[mi][ni][1]);
                v.z = f2bf(acc[mi][ni][2]);
                v.w = f2bf(acc[mi][ni][3]);
                *(ushort4*)&base[(size_t)(ni * 16 + c) * N_ + n0 + mi * 16 + 4 * g] = v;
            }
    }
}

// ---------------- Proj GEMM (round-4 128x128/BK=32 structure) + bias ----------------
__global__ __launch_bounds__(256)
void gemm_proj(const _Float16* __restrict__ Ag, const _Float16* __restrict__ Bg,
               const float* __restrict__ bias, float* __restrict__ Out)
{
    __shared__ __align__(16) unsigned char Ab[2][8192];
    __shared__ __align__(16) unsigned char Bb[2][8192];

    const int t    = threadIdx.x;
    const int lane = t & 63;
    const int w    = t >> 6;
    const int g    = lane >> 4;
    const int c    = lane & 15;
    const int wm   = w >> 1, wn = w & 1;
    const int bm   = blockIdx.y * 128;
    const int bn   = blockIdx.x * 128;
    constexpr int K = C_;

    f32x4 acc[4][4];
    f32x4 zero = {0.f, 0.f, 0.f, 0.f};
    #pragma unroll
    for (int mi = 0; mi < 4; ++mi)
        #pragma unroll
        for (int ni = 0; ni < 4; ++ni) acc[mi][ni] = zero;

    auto stage = [&](int buf, int k0) {
        #pragma unroll
        for (int i = 0; i < 2; ++i) {
            int id  = t + 256 * i;
            int ks  = id >> 7;
            int row = id & 127;
            int ldsb = (w * 64 + i * 256) * 16;
            async16(Ag + (size_t)(bm + row) * K + k0 + 8 * ks, &Ab[buf][ldsb]);
            async16(Bg + (size_t)(bn + row) * K + k0 + 8 * ks, &Bb[buf][ldsb]);
        }
    };

    stage(0, 0);
    __syncthreads();
    int cur = 0;

    for (int k0 = 0; k0 < K; k0 += 32) {
        if (k0 + 32 < K) stage(cur ^ 1, k0 + 32);

        const unsigned char* Abase = &Ab[cur][g * 2048];
        const unsigned char* Bbase = &Bb[cur][g * 2048];
        half8 af[4], bf[4];
        #pragma unroll
        for (int mi = 0; mi < 4; ++mi)
            af[mi] = *(const half8*)(Abase + (wm * 64 + mi * 16 + c) * 16);
        #pragma unroll
        for (int ni = 0; ni < 4; ++ni)
            bf[ni] = *(const half8*)(Bbase + (wn * 64 + ni * 16 + c) * 16);
        #pragma unroll
        for (int mi = 0; mi < 4; ++mi)
            #pragma unroll
            for (int ni = 0; ni < 4; ++ni)
                acc[mi][ni] = __builtin_amdgcn_mfma_f32_16x16x32_f16(af[mi], bf[ni], acc[mi][ni], 0, 0, 0);

        __syncthreads();
        cur ^= 1;
    }

    const int m0 = bm + wm * 64;
    const int o0 = bn + wn * 64;
    #pragma unroll
    for (int ni = 0; ni < 4; ++ni) {
        float bb = bias[o0 + ni * 16 + c];
        #pragma unroll
        for (int mi = 0; mi < 4; ++mi)
            #pragma unroll
            for (int r = 0; r < 4; ++r)
                Out[(size_t)(m0 + mi * 16 + 4 * g + r) * C_ + o0 + ni * 16 + c] =
                    acc[mi][ni][r] + bb;
    }
}

// ---------------- MFMA flash attention: 8 waves, 128 q rows per block ----------
__global__ __launch_bounds__(512)
void attn_mfma(const unsigned short* __restrict__ Qd, const unsigned short* __restrict__ Kd,
               const unsigned short* __restrict__ Vt, _Float16* __restrict__ AO)
{
    __shared__ __align__(16) unsigned char KsB[2][64 * 128];  // K tile  [key][d] bf16, swz
    __shared__ __align__(16) unsigned char VtB[2][64 * 128];  // V^T tile [d][key] bf16, swz
    __shared__ __align__(16) unsigned char Pb[8][16 * 128];   // per-wave P [q][key] bf16, swz

    const int t    = threadIdx.x;
    const int lane = t & 63;
    const int w    = t >> 6;                 // 0..7
    const int g    = lane >> 4;
    const int c    = lane & 15;
    const int cx   = c & 7;

    // bijective XCD swizzle: 512 blocks, 64 works/XCD -> 4 consecutive bh per XCD
    int flat = blockIdx.x;
    int work = (flat & 7) * 64 + (flat >> 3);
    const int bh = work >> 4;               // 0..31
    const int qt = work & 15;               // 0..15
    const int b  = bh >> 4, h = bh & 15;
    const int q0 = qt * 128;

    const unsigned short* Kp = Kd + (size_t)bh * N_ * D_;
    const unsigned short* Vp = Vt + (size_t)bh * D_ * N_;

    const unsigned short* qp = Qd + ((size_t)bh * N_ + q0 + w * 16 + c) * D_;
    bf16x8 qf0 = *(const bf16x8*)(qp + 8 * g);
    bf16x8 qf1 = *(const bf16x8*)(qp + 32 + 8 * g);

    const int rk = t >> 3, pk = t & 7;       // K: row 0..63, granule
    const unsigned char* kSrc = (const unsigned char*)Kp + rk * 128 + ((pk ^ (rk & 7)) << 4);
    const unsigned char* vSrc = (const unsigned char*)Vp + (size_t)rk * N_ * 2 + ((pk ^ (rk & 7)) << 4);
    unsigned char* kDstA = KsB[0] + t * 16;
    unsigned char* kDstB = KsB[1] + t * 16;
    unsigned char* vDstA = VtB[0] + t * 16;
    unsigned char* vDstB = VtB[1] + t * 16;

    float m_run = -1e30f, l_run = 0.f;
    f32x4 oc[4];
    f32x4 zero = {0.f, 0.f, 0.f, 0.f};
    #pragma unroll
    for (int dc = 0; dc < 4; ++dc) oc[dc] = zero;

    async16(kSrc, kDstA);
    async16(vSrc, vDstA);
    __syncthreads();

    int cur = 0;
    for (int kt = 0; kt < NTILES; ++kt) {
        if (kt + 1 < NTILES) {
            const unsigned char* ks = kSrc + (size_t)(kt + 1) * KVB * 128;
            const unsigned char* vs = vSrc + (size_t)(kt + 1) * 128;
            async16(ks, cur ? kDstA : kDstB);
            async16(vs, cur ? vDstA : vDstB);
        }

        // ---- S^T = K * Q^T  (rows = keys, cols = q = c) ----
        const unsigned char* kbase = KsB[cur];
        f32x4 st[4];
        #pragma unroll
        for (int tt = 0; tt < 4; ++tt) st[tt] = zero;
        __builtin_amdgcn_s_setprio(1);
        #pragma unroll
        for (int s = 0; s < 2; ++s) {
            bf16x8 qf = s ? qf1 : qf0;
            #pragma unroll
            for (int tt = 0; tt < 4; ++tt) {
                bf16x8 a = *(const bf16x8*)(kbase + (tt * 16 + c) * 128 + (((4 * s + g) ^ cx) << 4));
                st[tt] = __builtin_amdgcn_mfma_f32_16x16x32_bf16(a, qf, st[tt], 0, 0, 0);
            }
        }
        __builtin_amdgcn_s_setprio(0);

        // ---- online softmax with defer-max (THR = 8 in log2 domain) ----
        float mx = st[0][0];
        #pragma unroll
        for (int tt = 0; tt < 4; ++tt)
            #pragma unroll
            for (int r = 0; r < 4; ++r) mx = fmaxf(mx, st[tt][r]);
        mx = fmaxf(mx, __shfl_xor(mx, 16));
        mx = fmaxf(mx, __shfl_xor(mx, 32));
        const bool defer = __all(mx <= m_run + 8.f);
        const float nm = defer ? m_run : fmaxf(m_run, mx);
        float ts = 0.f;
        #pragma unroll
        for (int tt = 0; tt < 4; ++tt)
            #pragma unroll
            for (int r = 0; r < 4; ++r) {
                float p = exp2f(st[tt][r] - nm);
                st[tt][r] = p;
                ts += p;
            }
        ts += __shfl_xor(ts, 16);
        ts += __shfl_xor(ts, 32);
        if (defer) {
            l_run += ts;
        } else {
            float corr = exp2f(m_run - nm);
            l_run = l_run * corr + ts;
            m_run = nm;
            #pragma unroll
            for (int dc = 0; dc < 4; ++dc) oc[dc] *= corr;
        }

        // ---- pack P (truncate to bf16) -> wave-private LDS [q=c][key] ----
        unsigned char* pw = Pb[w] + c * 128;
        #pragma unroll
        for (int tt = 0; tt < 4; ++tt) {
            unsigned int lo = __byte_perm(__float_as_uint(st[tt][0]), __float_as_uint(st[tt][1]), 0x7632);
            unsigned int hi = __byte_perm(__float_as_uint(st[tt][2]), __float_as_uint(st[tt][3]), 0x7632);
            int gran = 2 * tt + (g >> 1);
            unsigned int* dst = (unsigned int*)(pw + ((gran ^ cx) << 4) + 8 * (g & 1));
            dst[0] = lo;
            dst[1] = hi;
        }

        // ---- out^T += V^T * P  (rows d, cols q = c) ----
        const unsigned char* vb = VtB[cur];
        const unsigned char* prd = Pb[w] + c * 128;
        bf16x8 pb0 = *(const bf16x8*)(prd + ((g ^ cx) << 4));
        bf16x8 pb1 = *(const bf16x8*)(prd + (((4 + g) ^ cx) << 4));
        __builtin_amdgcn_s_setprio(1);
        #pragma unroll
        for (int dc = 0; dc < 4; ++dc) {
            const unsigned char* vrow = vb + (dc * 16 + c) * 128;
            bf16x8 a0 = *(const bf16x8*)(vrow + ((g ^ cx) << 4));
            bf16x8 a1 = *(const bf16x8*)(vrow + (((4 + g) ^ cx) << 4));
            oc[dc] = __builtin_amdgcn_mfma_f32_16x16x32_bf16(a0, pb0, oc[dc], 0, 0, 0);
            oc[dc] = __builtin_amdgcn_mfma_f32_16x16x32_bf16(a1, pb1, oc[dc], 0, 0, 0);
        }
        __builtin_amdgcn_s_setprio(0);

        __syncthreads();   // drains vmcnt (stage done) + protects buffer swap
        cur ^= 1;
    }

    // ---- epilogue: normalize, write AO f16 [b][q][h*64+d] ----
    float inv = 1.0f / l_run;
    int q = q0 + w * 16 + c;
    _Float16* aop = AO + ((size_t)b * N_ + q) * C_ + h * D_;
    #pragma unroll
    for (int dc = 0; dc < 4; ++dc) {
        half4v o;
        o[0] = (_Float16)(oc[dc][0] * inv);
        o[1] = (_Float16)(oc[dc][1] * inv);
        o[2] = (_Float16)(oc[dc][2] * inv);
        o[3] = (_Float16)(oc[dc][3] * inv);
        *(half4v*)(aop + dc * 16 + 4 * g) = o;
    }
}

extern "C" void kernel_launch(void* const* d_in, const int* in_sizes, int n_in,
                              void* d_out, int out_size, void* d_ws, size_t ws_size,
                              hipStream_t stream) {
    const float* x      = (const float*)d_in[0];
    const float* w_qkv  = (const float*)d_in[1];
    const float* w_proj = (const float*)d_in[2];
    const float* b_proj = (const float*)d_in[3];
    float* out = (float*)d_out;

    const size_t hd = (size_t)B_ * H_ * N_ * D_;   // 4,194,304 elems
    unsigned short* Qd = (unsigned short*)d_ws;
    unsigned short* Kd = Qd + hd;
    unsigned short* Vt = Kd + hd;
    _Float16* AO  = (_Float16*)(Vt + hd);          // [B,N,C] f16
    _Float16* x16 = AO + hd;                       // [4096][1024]
    _Float16* wq16 = x16 + XN;                     // [3072][1024]
    _Float16* wp16 = wq16 + WQN;                   // [1024][1024]

    convert_f16<<<4096, 256, 0, stream>>>(x, w_qkv, w_proj, x16);
    gemm_qkv<<<dim3(O3 / 256, M_ / 256), 512, 0, stream>>>(x16, wq16, Qd, Kd, Vt);
    attn_mfma<<<dim3(512), 512, 0, stream>>>(Qd, Kd, Vt, AO);
    gemm_proj<<<dim3(C_ / 128, M_ / 128), 256, 0, stream>>>(AO, wp16, b_proj, out);
}

// Round 7
// 137.397 us; speedup vs baseline: 1.4440x; 1.3432x over previous
//
#include <hip/hip_runtime.h>

// CustomAttention: x[2,2048,1024] f32, w_qkv[3072,1024], w_proj[1024,1024], b_proj[1024]
// Round 7: fixed GEMM global-staging coalescing. LDS cell order now [row][granule]
//          (consecutive lanes -> consecutive 16B of one row = coalesced 128B spans),
//          with both-sides XOR swizzle (src granule p^(row&7), read granule
//          (s*4+g)^(row&7)) for conflict-free ds_read_b128. Both GEMMs 128^2/BK=64.
//   k0: convert_f16: x, w_qkv, w_proj f32 -> f16
//   k1: gemm128<0>: qkv -> Qd bf16 (scaled 0.125*log2e), Kd bf16, Vt bf16 [bh][d][n]
//   k2: attn_mfma (bf16 MFMA flash, 8 waves) -> AO f16 [b][n][C]
//   k3: gemm128<1>: proj + bias -> d_out f32

constexpr int B_ = 2, N_ = 2048, C_ = 1024, H_ = 16, D_ = 64;
constexpr int M_ = B_ * N_;   // 4096
constexpr int O3 = 3 * C_;    // 3072
constexpr int KVB = 64;
constexpr int NTILES = N_ / KVB;   // 32

typedef short bf16x8 __attribute__((ext_vector_type(8)));
typedef _Float16 half8 __attribute__((ext_vector_type(8)));
typedef _Float16 half4v __attribute__((ext_vector_type(4)));
typedef float f32x4  __attribute__((ext_vector_type(4)));

__device__ __forceinline__ unsigned short f2bf(float f) {
    unsigned int u = __float_as_uint(f);
    unsigned int r = (u + 0x7FFFu + ((u >> 16) & 1u)) >> 16;
    return (unsigned short)r;
}

__device__ __forceinline__ void async16(const void* g, void* l) {
    __builtin_amdgcn_global_load_lds(
        (const __attribute__((address_space(1))) unsigned int*)g,
        (__attribute__((address_space(3))) unsigned int*)l, 16, 0, 0);
}

// ---------------- f32 -> f16 convert (x | w_qkv | w_proj) ----------------
constexpr size_t XN  = (size_t)M_ * C_;        // 4,194,304
constexpr size_t WQN = (size_t)O3 * C_;        // 3,145,728
constexpr size_t WPN = (size_t)C_ * C_;        // 1,048,576

__global__ __launch_bounds__(256)
void convert_f16(const float* __restrict__ x, const float* __restrict__ wq,
                 const float* __restrict__ wp, _Float16* __restrict__ dst)
{
    size_t i = ((size_t)blockIdx.x * 256 + threadIdx.x) * 8;
    const float* src;
    size_t off;
    if (i < XN)            { src = x;  off = i; }
    else if (i < XN + WQN) { src = wq; off = i - XN; }
    else                   { src = wp; off = i - XN - WQN; }
    float4 a = *(const float4*)(src + off);
    float4 b = *(const float4*)(src + off + 4);
    half8 h;
    h[0] = (_Float16)a.x; h[1] = (_Float16)a.y; h[2] = (_Float16)a.z; h[3] = (_Float16)a.w;
    h[4] = (_Float16)b.x; h[5] = (_Float16)b.y; h[6] = (_Float16)b.z; h[7] = (_Float16)b.w;
    *(half8*)(dst + i) = h;
}

// ---------------- f16 MFMA GEMM: 128x128 tile, BK=64, coalesced staging ----------
// LDS per tile per operand: [row(0..127)][gran(0..7)][16B] = 16KB; dbuf -> 64KB.
// Stage: lane id = row*8+p loads global granule (row, p^(row&7)) -> LDS linear.
// Read: granule of k-slice (s*4+g) of row r lives at LDS gran (s*4+g)^(r&7):
//   16 c-lanes spread across 8 bank-quads (2-way, free).
// Frags (16x16x32): A row=lane&15, k=8*(lane>>4)+e ; B col=lane&15 same k ;
// C/D col=lane&15, row=4*(lane>>4)+reg.
template<int MODE>
__global__ __launch_bounds__(256)
void gemm128(const _Float16* __restrict__ Ag, const _Float16* __restrict__ Bg,
             unsigned short* __restrict__ Qd, unsigned short* __restrict__ Kd,
             unsigned short* __restrict__ Vt,
             const float* __restrict__ bias, float* __restrict__ Out)
{
    __shared__ __align__(16) unsigned char Ab[2][16384];
    __shared__ __align__(16) unsigned char Bb[2][16384];

    const int t    = threadIdx.x;
    const int lane = t & 63;
    const int w    = t >> 6;
    const int g    = lane >> 4;
    const int c    = lane & 15;
    const int wm   = w >> 1, wn = w & 1;
    const int bm   = blockIdx.y * 128;
    const int bn   = blockIdx.x * 128;
    constexpr int K = C_;

    f32x4 acc[4][4];
    f32x4 zero = {0.f, 0.f, 0.f, 0.f};
    #pragma unroll
    for (int mi = 0; mi < 4; ++mi)
        #pragma unroll
        for (int ni = 0; ni < 4; ++ni) acc[mi][ni] = zero;

    auto stage = [&](int buf, int k0) {
        #pragma unroll
        for (int i = 0; i < 4; ++i) {
            int id  = t + 256 * i;        // 0..1023 = row*8 + p
            int row = id >> 3;
            int p   = id & 7;
            int gs  = p ^ (row & 7);      // pre-swizzled source granule
            async16(Ag + (size_t)(bm + row) * K + k0 + 8 * gs, &Ab[buf][id * 16]);
            async16(Bg + (size_t)(bn + row) * K + k0 + 8 * gs, &Bb[buf][id * 16]);
        }
    };

    stage(0, 0);
    __syncthreads();
    int cur = 0;

    for (int k0 = 0; k0 < K; k0 += 64) {
        if (k0 + 64 < K) stage(cur ^ 1, k0 + 64);   // prefetch next tile

        const unsigned char* Abase = Ab[cur];
        const unsigned char* Bbase = Bb[cur];
        #pragma unroll
        for (int s = 0; s < 2; ++s) {               // two k-slices of 32
            half8 af[4], bf[4];
            #pragma unroll
            for (int mi = 0; mi < 4; ++mi) {
                int row = wm * 64 + mi * 16 + c;
                af[mi] = *(const half8*)(Abase + (row * 8 + ((s * 4 + g) ^ (row & 7))) * 16);
            }
            #pragma unroll
            for (int ni = 0; ni < 4; ++ni) {
                int row = wn * 64 + ni * 16 + c;
                bf[ni] = *(const half8*)(Bbase + (row * 8 + ((s * 4 + g) ^ (row & 7))) * 16);
            }
            #pragma unroll
            for (int mi = 0; mi < 4; ++mi)
                #pragma unroll
                for (int ni = 0; ni < 4; ++ni)
                    acc[mi][ni] = __builtin_amdgcn_mfma_f32_16x16x32_f16(af[mi], bf[ni], acc[mi][ni], 0, 0, 0);
        }

        __syncthreads();   // drains this iter's prefetch + protects buffer swap
        cur ^= 1;
    }

    if constexpr (MODE == 0) {
        // scatter epilogue: o = which*1024 + h*64 + d (64-col wave region = one head)
        constexpr float QSCALE = 0.125f * 1.4426950408889634f;   // D^-0.5 * log2(e)
        const int o0 = bn + wn * 64;
        const int which = o0 >> 10;
        const int h  = (o0 & 1023) >> 6;
        const int m0 = bm + wm * 64;
        const int b  = m0 >> 11;
        const int n0 = m0 & 2047;
        const size_t bh = (size_t)b * H_ + h;
        if (which == 0) {
            unsigned short* base = Qd + (bh * N_) * D_;
            #pragma unroll
            for (int mi = 0; mi < 4; ++mi)
                #pragma unroll
                for (int ni = 0; ni < 4; ++ni)
                    #pragma unroll
                    for (int r = 0; r < 4; ++r)
                        base[(size_t)(n0 + mi * 16 + 4 * g + r) * D_ + ni * 16 + c] =
                            f2bf(acc[mi][ni][r] * QSCALE);
        } else if (which == 1) {
            unsigned short* base = Kd + (bh * N_) * D_;
            #pragma unroll
            for (int mi = 0; mi < 4; ++mi)
                #pragma unroll
                for (int ni = 0; ni < 4; ++ni)
                    #pragma unroll
                    for (int r = 0; r < 4; ++r)
                        base[(size_t)(n0 + mi * 16 + 4 * g + r) * D_ + ni * 16 + c] =
                            f2bf(acc[mi][ni][r]);
        } else {
            unsigned short* base = Vt + (bh * D_) * (size_t)N_;
            #pragma unroll
            for (int mi = 0; mi < 4; ++mi)
                #pragma unroll
                for (int ni = 0; ni < 4; ++ni) {
                    ushort4 v;
                    v.x = f2bf(acc[mi][ni][0]);
                    v.y = f2bf(acc[mi][ni][1]);
                    v.z = f2bf(acc[mi][ni][2]);
                    v.w = f2bf(acc[mi][ni][3]);
                    *(ushort4*)&base[(size_t)(ni * 16 + c) * N_ + n0 + mi * 16 + 4 * g] = v;
                }
        }
    } else {
        const int m0 = bm + wm * 64;
        const int o0 = bn + wn * 64;
        #pragma unroll
        for (int ni = 0; ni < 4; ++ni) {
            float bb = bias[o0 + ni * 16 + c];
            #pragma unroll
            for (int mi = 0; mi < 4; ++mi)
                #pragma unroll
                for (int r = 0; r < 4; ++r)
                    Out[(size_t)(m0 + mi * 16 + 4 * g + r) * C_ + o0 + ni * 16 + c] =
                        acc[mi][ni][r] + bb;
        }
    }
}

// ---------------- MFMA flash attention: 8 waves, 128 q rows per block ----------
__global__ __launch_bounds__(512)
void attn_mfma(const unsigned short* __restrict__ Qd, const unsigned short* __restrict__ Kd,
               const unsigned short* __restrict__ Vt, _Float16* __restrict__ AO)
{
    __shared__ __align__(16) unsigned char KsB[2][64 * 128];  // K tile  [key][d] bf16, swz
    __shared__ __align__(16) unsigned char VtB[2][64 * 128];  // V^T tile [d][key] bf16, swz
    __shared__ __align__(16) unsigned char Pb[8][16 * 128];   // per-wave P [q][key] bf16, swz

    const int t    = threadIdx.x;
    const int lane = t & 63;
    const int w    = t >> 6;                 // 0..7
    const int g    = lane >> 4;
    const int c    = lane & 15;
    const int cx   = c & 7;

    // bijective XCD swizzle: 512 blocks, 64 works/XCD -> 4 consecutive bh per XCD
    int flat = blockIdx.x;
    int work = (flat & 7) * 64 + (flat >> 3);
    const int bh = work >> 4;               // 0..31
    const int qt = work & 15;               // 0..15
    const int b  = bh >> 4, h = bh & 15;
    const int q0 = qt * 128;

    const unsigned short* Kp = Kd + (size_t)bh * N_ * D_;
    const unsigned short* Vp = Vt + (size_t)bh * D_ * N_;

    const unsigned short* qp = Qd + ((size_t)bh * N_ + q0 + w * 16 + c) * D_;
    bf16x8 qf0 = *(const bf16x8*)(qp + 8 * g);
    bf16x8 qf1 = *(const bf16x8*)(qp + 32 + 8 * g);

    const int rk = t >> 3, pk = t & 7;       // K: row 0..63, granule
    const unsigned char* kSrc = (const unsigned char*)Kp + rk * 128 + ((pk ^ (rk & 7)) << 4);
    const unsigned char* vSrc = (const unsigned char*)Vp + (size_t)rk * N_ * 2 + ((pk ^ (rk & 7)) << 4);
    unsigned char* kDstA = KsB[0] + t * 16;
    unsigned char* kDstB = KsB[1] + t * 16;
    unsigned char* vDstA = VtB[0] + t * 16;
    unsigned char* vDstB = VtB[1] + t * 16;

    float m_run = -1e30f, l_run = 0.f;
    f32x4 oc[4];
    f32x4 zero = {0.f, 0.f, 0.f, 0.f};
    #pragma unroll
    for (int dc = 0; dc < 4; ++dc) oc[dc] = zero;

    async16(kSrc, kDstA);
    async16(vSrc, vDstA);
    __syncthreads();

    int cur = 0;
    for (int kt = 0; kt < NTILES; ++kt) {
        if (kt + 1 < NTILES) {
            const unsigned char* ks = kSrc + (size_t)(kt + 1) * KVB * 128;
            const unsigned char* vs = vSrc + (size_t)(kt + 1) * 128;
            async16(ks, cur ? kDstA : kDstB);
            async16(vs, cur ? vDstA : vDstB);
        }

        // ---- S^T = K * Q^T  (rows = keys, cols = q = c) ----
        const unsigned char* kbase = KsB[cur];
        f32x4 st[4];
        #pragma unroll
        for (int tt = 0; tt < 4; ++tt) st[tt] = zero;
        __builtin_amdgcn_s_setprio(1);
        #pragma unroll
        for (int s = 0; s < 2; ++s) {
            bf16x8 qf = s ? qf1 : qf0;
            #pragma unroll
            for (int tt = 0; tt < 4; ++tt) {
                bf16x8 a = *(const bf16x8*)(kbase + (tt * 16 + c) * 128 + (((4 * s + g) ^ cx) << 4));
                st[tt] = __builtin_amdgcn_mfma_f32_16x16x32_bf16(a, qf, st[tt], 0, 0, 0);
            }
        }
        __builtin_amdgcn_s_setprio(0);

        // ---- online softmax with defer-max (THR = 8 in log2 domain) ----
        float mx = st[0][0];
        #pragma unroll
        for (int tt = 0; tt < 4; ++tt)
            #pragma unroll
            for (int r = 0; r < 4; ++r) mx = fmaxf(mx, st[tt][r]);
        mx = fmaxf(mx, __shfl_xor(mx, 16));
        mx = fmaxf(mx, __shfl_xor(mx, 32));
        const bool defer = __all(mx <= m_run + 8.f);
        const float nm = defer ? m_run : fmaxf(m_run, mx);
        float ts = 0.f;
        #pragma unroll
        for (int tt = 0; tt < 4; ++tt)
            #pragma unroll
            for (int r = 0; r < 4; ++r) {
                float p = exp2f(st[tt][r] - nm);
                st[tt][r] = p;
                ts += p;
            }
        ts += __shfl_xor(ts, 16);
        ts += __shfl_xor(ts, 32);
        if (defer) {
            l_run += ts;
        } else {
            float corr = exp2f(m_run - nm);
            l_run = l_run * corr + ts;
            m_run = nm;
            #pragma unroll
            for (int dc = 0; dc < 4; ++dc) oc[dc] *= corr;
        }

        // ---- pack P (truncate to bf16) -> wave-private LDS [q=c][key] ----
        unsigned char* pw = Pb[w] + c * 128;
        #pragma unroll
        for (int tt = 0; tt < 4; ++tt) {
            unsigned int lo = __byte_perm(__float_as_uint(st[tt][0]), __float_as_uint(st[tt][1]), 0x7632);
            unsigned int hi = __byte_perm(__float_as_uint(st[tt][2]), __float_as_uint(st[tt][3]), 0x7632);
            int gran = 2 * tt + (g >> 1);
            unsigned int* dst = (unsigned int*)(pw + ((gran ^ cx) << 4) + 8 * (g & 1));
            dst[0] = lo;
            dst[1] = hi;
        }

        // ---- out^T += V^T * P  (rows d, cols q = c) ----
        const unsigned char* vb = VtB[cur];
        const unsigned char* prd = Pb[w] + c * 128;
        bf16x8 pb0 = *(const bf16x8*)(prd + ((g ^ cx) << 4));
        bf16x8 pb1 = *(const bf16x8*)(prd + (((4 + g) ^ cx) << 4));
        __builtin_amdgcn_s_setprio(1);
        #pragma unroll
        for (int dc = 0; dc < 4; ++dc) {
            const unsigned char* vrow = vb + (dc * 16 + c) * 128;
            bf16x8 a0 = *(const bf16x8*)(vrow + ((g ^ cx) << 4));
            bf16x8 a1 = *(const bf16x8*)(vrow + (((4 + g) ^ cx) << 4));
            oc[dc] = __builtin_amdgcn_mfma_f32_16x16x32_bf16(a0, pb0, oc[dc], 0, 0, 0);
            oc[dc] = __builtin_amdgcn_mfma_f32_16x16x32_bf16(a1, pb1, oc[dc], 0, 0, 0);
        }
        __builtin_amdgcn_s_setprio(0);

        __syncthreads();   // drains vmcnt (stage done) + protects buffer swap
        cur ^= 1;
    }

    // ---- epilogue: normalize, write AO f16 [b][q][h*64+d] ----
    float inv = 1.0f / l_run;
    int q = q0 + w * 16 + c;
    _Float16* aop = AO + ((size_t)b * N_ + q) * C_ + h * D_;
    #pragma unroll
    for (int dc = 0; dc < 4; ++dc) {
        half4v o;
        o[0] = (_Float16)(oc[dc][0] * inv);
        o[1] = (_Float16)(oc[dc][1] * inv);
        o[2] = (_Float16)(oc[dc][2] * inv);
        o[3] = (_Float16)(oc[dc][3] * inv);
        *(half4v*)(aop + dc * 16 + 4 * g) = o;
    }
}

extern "C" void kernel_launch(void* const* d_in, const int* in_sizes, int n_in,
                              void* d_out, int out_size, void* d_ws, size_t ws_size,
                              hipStream_t stream) {
    const float* x      = (const float*)d_in[0];
    const float* w_qkv  = (const float*)d_in[1];
    const float* w_proj = (const float*)d_in[2];
    const float* b_proj = (const float*)d_in[3];
    float* out = (float*)d_out;

    const size_t hd = (size_t)B_ * H_ * N_ * D_;   // 4,194,304 elems
    unsigned short* Qd = (unsigned short*)d_ws;
    unsigned short* Kd = Qd + hd;
    unsigned short* Vt = Kd + hd;
    _Float16* AO  = (_Float16*)(Vt + hd);          // [B,N,C] f16
    _Float16* x16 = AO + hd;                       // [4096][1024]
    _Float16* wq16 = x16 + XN;                     // [3072][1024]
    _Float16* wp16 = wq16 + WQN;                   // [1024][1024]

    convert_f16<<<4096, 256, 0, stream>>>(x, w_qkv, w_proj, x16);
    gemm128<0><<<dim3(O3 / 128, M_ / 128), 256, 0, stream>>>(
        x16, wq16, Qd, Kd, Vt, nullptr, nullptr);
    attn_mfma<<<dim3(512), 512, 0, stream>>>(Qd, Kd, Vt, AO);
    gemm128<1><<<dim3(C_ / 128, M_ / 128), 256, 0, stream>>>(
        AO, wp16, nullptr, nullptr, nullptr, b_proj, out);
}

// Round 8
// 134.597 us; speedup vs baseline: 1.4740x; 1.0208x over previous
//
#include <hip/hip_runtime.h>

// CustomAttention: x[2,2048,1024] f32, w_qkv[3072,1024], w_proj[1024,1024], b_proj[1024]
// Round 8: attention VALU-diet: (1) kt-loop unrolled x2 with static LDS buffers
//          (address invariance), (2) softmax denominator via ones-row MFMA (lsum
//          rides in the matrix pipe, rescale/defer applies identically), (3) max3
//          tree reduction. GEMMs unchanged from round 7.
//   k0: convert_f16: x, w_qkv, w_proj f32 -> f16
//   k1: gemm128<0>: qkv -> Qd bf16 (scaled 0.125*log2e), Kd bf16, Vt bf16 [bh][d][n]
//   k2: attn_mfma (bf16 MFMA flash, 8 waves, 128 q rows) -> AO f16 [b][n][C]
//   k3: gemm128<1>: proj + bias -> d_out f32

constexpr int B_ = 2, N_ = 2048, C_ = 1024, H_ = 16, D_ = 64;
constexpr int M_ = B_ * N_;   // 4096
constexpr int O3 = 3 * C_;    // 3072
constexpr int KVB = 64;
constexpr int NTILES = N_ / KVB;   // 32

typedef short bf16x8 __attribute__((ext_vector_type(8)));
typedef _Float16 half8 __attribute__((ext_vector_type(8)));
typedef _Float16 half4v __attribute__((ext_vector_type(4)));
typedef float f32x4  __attribute__((ext_vector_type(4)));

__device__ __forceinline__ unsigned short f2bf(float f) {
    unsigned int u = __float_as_uint(f);
    unsigned int r = (u + 0x7FFFu + ((u >> 16) & 1u)) >> 16;
    return (unsigned short)r;
}

__device__ __forceinline__ void async16(const void* g, void* l) {
    __builtin_amdgcn_global_load_lds(
        (const __attribute__((address_space(1))) unsigned int*)g,
        (__attribute__((address_space(3))) unsigned int*)l, 16, 0, 0);
}

// ---------------- f32 -> f16 convert (x | w_qkv | w_proj) ----------------
constexpr size_t XN  = (size_t)M_ * C_;        // 4,194,304
constexpr size_t WQN = (size_t)O3 * C_;        // 3,145,728
constexpr size_t WPN = (size_t)C_ * C_;        // 1,048,576

__global__ __launch_bounds__(256)
void convert_f16(const float* __restrict__ x, const float* __restrict__ wq,
                 const float* __restrict__ wp, _Float16* __restrict__ dst)
{
    size_t i = ((size_t)blockIdx.x * 256 + threadIdx.x) * 8;
    const float* src;
    size_t off;
    if (i < XN)            { src = x;  off = i; }
    else if (i < XN + WQN) { src = wq; off = i - XN; }
    else                   { src = wp; off = i - XN - WQN; }
    float4 a = *(const float4*)(src + off);
    float4 b = *(const float4*)(src + off + 4);
    half8 h;
    h[0] = (_Float16)a.x; h[1] = (_Float16)a.y; h[2] = (_Float16)a.z; h[3] = (_Float16)a.w;
    h[4] = (_Float16)b.x; h[5] = (_Float16)b.y; h[6] = (_Float16)b.z; h[7] = (_Float16)b.w;
    *(half8*)(dst + i) = h;
}

// ---------------- f16 MFMA GEMM: 128x128 tile, BK=64, coalesced staging ----------
template<int MODE>
__global__ __launch_bounds__(256)
void gemm128(const _Float16* __restrict__ Ag, const _Float16* __restrict__ Bg,
             unsigned short* __restrict__ Qd, unsigned short* __restrict__ Kd,
             unsigned short* __restrict__ Vt,
             const float* __restrict__ bias, float* __restrict__ Out)
{
    __shared__ __align__(16) unsigned char Ab[2][16384];
    __shared__ __align__(16) unsigned char Bb[2][16384];

    const int t    = threadIdx.x;
    const int lane = t & 63;
    const int w    = t >> 6;
    const int g    = lane >> 4;
    const int c    = lane & 15;
    const int wm   = w >> 1, wn = w & 1;
    const int bm   = blockIdx.y * 128;
    const int bn   = blockIdx.x * 128;
    constexpr int K = C_;

    f32x4 acc[4][4];
    f32x4 zero = {0.f, 0.f, 0.f, 0.f};
    #pragma unroll
    for (int mi = 0; mi < 4; ++mi)
        #pragma unroll
        for (int ni = 0; ni < 4; ++ni) acc[mi][ni] = zero;

    auto stage = [&](int buf, int k0) {
        #pragma unroll
        for (int i = 0; i < 4; ++i) {
            int id  = t + 256 * i;        // 0..1023 = row*8 + p
            int row = id >> 3;
            int p   = id & 7;
            int gs  = p ^ (row & 7);      // pre-swizzled source granule
            async16(Ag + (size_t)(bm + row) * K + k0 + 8 * gs, &Ab[buf][id * 16]);
            async16(Bg + (size_t)(bn + row) * K + k0 + 8 * gs, &Bb[buf][id * 16]);
        }
    };

    stage(0, 0);
    __syncthreads();
    int cur = 0;

    for (int k0 = 0; k0 < K; k0 += 64) {
        if (k0 + 64 < K) stage(cur ^ 1, k0 + 64);   // prefetch next tile

        const unsigned char* Abase = Ab[cur];
        const unsigned char* Bbase = Bb[cur];
        #pragma unroll
        for (int s = 0; s < 2; ++s) {               // two k-slices of 32
            half8 af[4], bf[4];
            #pragma unroll
            for (int mi = 0; mi < 4; ++mi) {
                int row = wm * 64 + mi * 16 + c;
                af[mi] = *(const half8*)(Abase + (row * 8 + ((s * 4 + g) ^ (row & 7))) * 16);
            }
            #pragma unroll
            for (int ni = 0; ni < 4; ++ni) {
                int row = wn * 64 + ni * 16 + c;
                bf[ni] = *(const half8*)(Bbase + (row * 8 + ((s * 4 + g) ^ (row & 7))) * 16);
            }
            #pragma unroll
            for (int mi = 0; mi < 4; ++mi)
                #pragma unroll
                for (int ni = 0; ni < 4; ++ni)
                    acc[mi][ni] = __builtin_amdgcn_mfma_f32_16x16x32_f16(af[mi], bf[ni], acc[mi][ni], 0, 0, 0);
        }

        __syncthreads();   // drains this iter's prefetch + protects buffer swap
        cur ^= 1;
    }

    if constexpr (MODE == 0) {
        // scatter epilogue: o = which*1024 + h*64 + d (64-col wave region = one head)
        constexpr float QSCALE = 0.125f * 1.4426950408889634f;   // D^-0.5 * log2(e)
        const int o0 = bn + wn * 64;
        const int which = o0 >> 10;
        const int h  = (o0 & 1023) >> 6;
        const int m0 = bm + wm * 64;
        const int b  = m0 >> 11;
        const int n0 = m0 & 2047;
        const size_t bh = (size_t)b * H_ + h;
        if (which == 0) {
            unsigned short* base = Qd + (bh * N_) * D_;
            #pragma unroll
            for (int mi = 0; mi < 4; ++mi)
                #pragma unroll
                for (int ni = 0; ni < 4; ++ni)
                    #pragma unroll
                    for (int r = 0; r < 4; ++r)
                        base[(size_t)(n0 + mi * 16 + 4 * g + r) * D_ + ni * 16 + c] =
                            f2bf(acc[mi][ni][r] * QSCALE);
        } else if (which == 1) {
            unsigned short* base = Kd + (bh * N_) * D_;
            #pragma unroll
            for (int mi = 0; mi < 4; ++mi)
                #pragma unroll
                for (int ni = 0; ni < 4; ++ni)
                    #pragma unroll
                    for (int r = 0; r < 4; ++r)
                        base[(size_t)(n0 + mi * 16 + 4 * g + r) * D_ + ni * 16 + c] =
                            f2bf(acc[mi][ni][r]);
        } else {
            unsigned short* base = Vt + (bh * D_) * (size_t)N_;
            #pragma unroll
            for (int mi = 0; mi < 4; ++mi)
                #pragma unroll
                for (int ni = 0; ni < 4; ++ni) {
                    ushort4 v;
                    v.x = f2bf(acc[mi][ni][0]);
                    v.y = f2bf(acc[mi][ni][1]);
                    v.z = f2bf(acc[mi][ni][2]);
                    v.w = f2bf(acc[mi][ni][3]);
                    *(ushort4*)&base[(size_t)(ni * 16 + c) * N_ + n0 + mi * 16 + 4 * g] = v;
                }
        }
    } else {
        const int m0 = bm + wm * 64;
        const int o0 = bn + wn * 64;
        #pragma unroll
        for (int ni = 0; ni < 4; ++ni) {
            float bb = bias[o0 + ni * 16 + c];
            #pragma unroll
            for (int mi = 0; mi < 4; ++mi)
                #pragma unroll
                for (int r = 0; r < 4; ++r)
                    Out[(size_t)(m0 + mi * 16 + 4 * g + r) * C_ + o0 + ni * 16 + c] =
                        acc[mi][ni][r] + bb;
        }
    }
}

// ---------------- MFMA flash attention: 8 waves, 128 q rows per block ----------
// Frags (16x16x32): A row=lane&15, k=8*(lane>>4)+e ; B col=lane&15 same k ;
// C/D col=lane&15, row=4*(lane>>4)+reg.
__global__ __launch_bounds__(512)
void attn_mfma(const unsigned short* __restrict__ Qd, const unsigned short* __restrict__ Kd,
               const unsigned short* __restrict__ Vt, _Float16* __restrict__ AO)
{
    __shared__ __align__(16) unsigned char KsB[2][64 * 128];  // K tile  [key][d] bf16, swz
    __shared__ __align__(16) unsigned char VtB[2][64 * 128];  // V^T tile [d][key] bf16, swz
    __shared__ __align__(16) unsigned char Pb[8][16 * 128];   // per-wave P [q][key] bf16, swz

    const int t    = threadIdx.x;
    const int lane = t & 63;
    const int w    = t >> 6;                 // 0..7
    const int g    = lane >> 4;
    const int c    = lane & 15;
    const int cx   = c & 7;

    // bijective XCD swizzle: 512 blocks, 64 works/XCD -> 4 consecutive bh per XCD
    int flat = blockIdx.x;
    int work = (flat & 7) * 64 + (flat >> 3);
    const int bh = work >> 4;               // 0..31
    const int qt = work & 15;               // 0..15
    const int b  = bh >> 4, h = bh & 15;
    const int q0 = qt * 128;

    const unsigned short* Kp = Kd + (size_t)bh * N_ * D_;
    const unsigned short* Vp = Vt + (size_t)bh * D_ * N_;

    const unsigned short* qp = Qd + ((size_t)bh * N_ + q0 + w * 16 + c) * D_;
    bf16x8 qf0 = *(const bf16x8*)(qp + 8 * g);
    bf16x8 qf1 = *(const bf16x8*)(qp + 32 + 8 * g);

    const int rk = t >> 3, pk = t & 7;       // K: row 0..63, granule
    const unsigned char* kSrc = (const unsigned char*)Kp + rk * 128 + ((pk ^ (rk & 7)) << 4);
    const unsigned char* vSrc = (const unsigned char*)Vp + (size_t)rk * N_ * 2 + ((pk ^ (rk & 7)) << 4);
    unsigned char* kDstA = KsB[0] + t * 16;
    unsigned char* kDstB = KsB[1] + t * 16;
    unsigned char* vDstA = VtB[0] + t * 16;
    unsigned char* vDstB = VtB[1] + t * 16;

    // ones-row A-fragment for the denominator MFMA: V^T row 64 = 1, rows 65..79 = 0.
    // Lane (g,c) supplies A row 64+c, so only c==0 lanes carry ones.
    bf16x8 aone;
    {
        short onev = (c == 0) ? (short)0x3F80 : (short)0;
        #pragma unroll
        for (int e = 0; e < 8; ++e) aone[e] = onev;
    }

    float m_run = -1e30f;
    f32x4 oc[4];
    f32x4 lsum;
    f32x4 zero = {0.f, 0.f, 0.f, 0.f};
    #pragma unroll
    for (int dc = 0; dc < 4; ++dc) oc[dc] = zero;
    lsum = zero;

    async16(kSrc, kDstA);
    async16(vSrc, vDstA);
    __syncthreads();

    unsigned char* pw  = Pb[w] + c * 128;
    const unsigned char* prd = Pb[w] + c * 128;

    auto tile_body = [&](const unsigned char* kbase, const unsigned char* vb,
                         unsigned char* kDstN, unsigned char* vDstN, int ktNext) {
        if (ktNext < NTILES) {
            async16(kSrc + (size_t)ktNext * KVB * 128, kDstN);
            async16(vSrc + (size_t)ktNext * 128, vDstN);
        }

        // ---- S^T = K * Q^T  (rows = keys, cols = q = c) ----
        f32x4 st[4];
        #pragma unroll
        for (int tt = 0; tt < 4; ++tt) st[tt] = zero;
        __builtin_amdgcn_s_setprio(1);
        #pragma unroll
        for (int s = 0; s < 2; ++s) {
            bf16x8 qf = s ? qf1 : qf0;
            #pragma unroll
            for (int tt = 0; tt < 4; ++tt) {
                bf16x8 a = *(const bf16x8*)(kbase + (tt * 16 + c) * 128 + (((4 * s + g) ^ cx) << 4));
                st[tt] = __builtin_amdgcn_mfma_f32_16x16x32_bf16(a, qf, st[tt], 0, 0, 0);
            }
        }
        __builtin_amdgcn_s_setprio(0);

        // ---- tile max: max3-fused tree + 2 cross-lane ----
        float t0 = fmaxf(fmaxf(st[0][0], st[0][1]), st[0][2]);
        float t1 = fmaxf(fmaxf(st[0][3], st[1][0]), st[1][1]);
        float t2 = fmaxf(fmaxf(st[1][2], st[1][3]), st[2][0]);
        float t3 = fmaxf(fmaxf(st[2][1], st[2][2]), st[2][3]);
        float t4 = fmaxf(fmaxf(st[3][0], st[3][1]), st[3][2]);
        float mx = fmaxf(fmaxf(fmaxf(t0, t1), fmaxf(t2, t3)), fmaxf(t4, st[3][3]));
        mx = fmaxf(mx, __shfl_xor(mx, 16));
        mx = fmaxf(mx, __shfl_xor(mx, 32));

        // ---- defer-max (THR = 8 in log2 domain): P bounded by 2^8 ----
        const bool defer = __all(mx <= m_run + 8.f);
        if (!defer) {
            const float nm = fmaxf(m_run, mx);
            const float corr = exp2f(m_run - nm);
            m_run = nm;
            #pragma unroll
            for (int dc = 0; dc < 4; ++dc) oc[dc] *= corr;
            lsum[0] *= corr;
        }
        const float nm = m_run;
        #pragma unroll
        for (int tt = 0; tt < 4; ++tt)
            #pragma unroll
            for (int r = 0; r < 4; ++r)
                st[tt][r] = exp2f(st[tt][r] - nm);

        // ---- pack P (truncate to bf16) -> wave-private LDS [q=c][key] ----
        #pragma unroll
        for (int tt = 0; tt < 4; ++tt) {
            unsigned int lo = __byte_perm(__float_as_uint(st[tt][0]), __float_as_uint(st[tt][1]), 0x7632);
            unsigned int hi = __byte_perm(__float_as_uint(st[tt][2]), __float_as_uint(st[tt][3]), 0x7632);
            int gran = 2 * tt + (g >> 1);
            unsigned int* dst = (unsigned int*)(pw + ((gran ^ cx) << 4) + 8 * (g & 1));
            dst[0] = lo;
            dst[1] = hi;
        }

        // ---- out^T += V^T * P ; denominator rides as ones-row MFMA ----
        bf16x8 pb0 = *(const bf16x8*)(prd + ((g ^ cx) << 4));
        bf16x8 pb1 = *(const bf16x8*)(prd + (((4 + g) ^ cx) << 4));
        __builtin_amdgcn_s_setprio(1);
        #pragma unroll
        for (int dc = 0; dc < 4; ++dc) {
            const unsigned char* vrow = vb + (dc * 16 + c) * 128;
            bf16x8 a0 = *(const bf16x8*)(vrow + ((g ^ cx) << 4));
            bf16x8 a1 = *(const bf16x8*)(vrow + (((4 + g) ^ cx) << 4));
            oc[dc] = __builtin_amdgcn_mfma_f32_16x16x32_bf16(a0, pb0, oc[dc], 0, 0, 0);
            oc[dc] = __builtin_amdgcn_mfma_f32_16x16x32_bf16(a1, pb1, oc[dc], 0, 0, 0);
        }
        lsum = __builtin_amdgcn_mfma_f32_16x16x32_bf16(aone, pb0, lsum, 0, 0, 0);
        lsum = __builtin_amdgcn_mfma_f32_16x16x32_bf16(aone, pb1, lsum, 0, 0, 0);
        __builtin_amdgcn_s_setprio(0);

        __syncthreads();   // drains vmcnt (stage done) + protects buffer swap
    };

    #pragma unroll 1
    for (int kt = 0; kt < NTILES; kt += 2) {
        tile_body(KsB[0], VtB[0], kDstB, vDstB, kt + 1);
        tile_body(KsB[1], VtB[1], kDstA, vDstA, kt + 2);
    }

    // ---- epilogue: broadcast l from lane c (g=0 holds row 64), normalize ----
    float l = __shfl(lsum[0], c);
    float inv = 1.0f / l;
    int q = q0 + w * 16 + c;
    _Float16* aop = AO + ((size_t)b * N_ + q) * C_ + h * D_;
    #pragma unroll
    for (int dc = 0; dc < 4; ++dc) {
        half4v o;
        o[0] = (_Float16)(oc[dc][0] * inv);
        o[1] = (_Float16)(oc[dc][1] * inv);
        o[2] = (_Float16)(oc[dc][2] * inv);
        o[3] = (_Float16)(oc[dc][3] * inv);
        *(half4v*)(aop + dc * 16 + 4 * g) = o;
    }
}

extern "C" void kernel_launch(void* const* d_in, const int* in_sizes, int n_in,
                              void* d_out, int out_size, void* d_ws, size_t ws_size,
                              hipStream_t stream) {
    const float* x      = (const float*)d_in[0];
    const float* w_qkv  = (const float*)d_in[1];
    const float* w_proj = (const float*)d_in[2];
    const float* b_proj = (const float*)d_in[3];
    float* out = (float*)d_out;

    const size_t hd = (size_t)B_ * H_ * N_ * D_;   // 4,194,304 elems
    unsigned short* Qd = (unsigned short*)d_ws;
    unsigned short* Kd = Qd + hd;
    unsigned short* Vt = Kd + hd;
    _Float16* AO  = (_Float16*)(Vt + hd);          // [B,N,C] f16
    _Float16* x16 = AO + hd;                       // [4096][1024]
    _Float16* wq16 = x16 + XN;                     // [3072][1024]
    _Float16* wp16 = wq16 + WQN;                   // [1024][1024]

    convert_f16<<<4096, 256, 0, stream>>>(x, w_qkv, w_proj, x16);
    gemm128<0><<<dim3(O3 / 128, M_ / 128), 256, 0, stream>>>(
        x16, wq16, Qd, Kd, Vt, nullptr, nullptr);
    attn_mfma<<<dim3(512), 512, 0, stream>>>(Qd, Kd, Vt, AO);
    gemm128<1><<<dim3(C_ / 128, M_ / 128), 256, 0, stream>>>(
        AO, wp16, nullptr, nullptr, nullptr, b_proj, out);
}